// Round 2
// baseline (302.672 us; speedup 1.0000x reference)
//
#include <hip/hip_runtime.h>
#include <hip/hip_bf16.h>
#include <math.h>

#define NB 512
#define NS 200
#define NH 256
#define TILE_S 32
#define LDSPAD 8
#define LDW (NH + LDSPAD)        // 264 bf16 row stride (528 B = 33*16 -> 16B aligned, +4 bank shift/row)
#define WS_STRIDE 258            // per (b,half): [m, Z, pooled[256]]

typedef __bf16 bf16x8 __attribute__((ext_vector_type(8)));
typedef float  f32x4  __attribute__((ext_vector_type(4)));

__device__ __forceinline__ float tanh_fast(float x) {
  float xc = fminf(fmaxf(x, -10.f), 10.f);
  float e  = __expf(2.f * xc);
  return (e - 1.f) / (e + 1.f);
}

// ---------------- Kernel 1: partial attention over an S-range ----------------
// grid = 1024: block (b, half). half 0 -> s in [0,96) (3 tiles), half 1 -> s in [96,200) (4 tiles).
__global__ __launch_bounds__(256, 4)
void fused_meta_attn_part(const float* __restrict__ mem,    // [B,S,H]
                          const float* __restrict__ lastm,  // [B,H]
                          const float* __restrict__ U,      // [H,H]
                          const float* __restrict__ W,      // [H,H]
                          const float* __restrict__ V,      // [H]
                          float* __restrict__ ws)           // [B*2, WS_STRIDE]
{
  const int b    = blockIdx.x >> 1;
  const int half = blockIdx.x & 1;
  const int s_begin = half ? 96 : 0;
  const int s_end   = half ? NS : 96;
  const int ntiles  = half ? 4 : 3;

  const int t    = threadIdx.x;   // 0..255
  const int wave = t >> 6;
  const int lane = t & 63;
  const int m16  = lane & 15;
  const int quad = lane >> 4;

  __shared__ __align__(16) __bf16 mem_sm[TILE_S][LDW];  // 16.9 KB
  __shared__ float lm_sm[NH];
  __shared__ float l_sm[NH];
  __shared__ float v_sm[NH];
  __shared__ float swave_sm[4][TILE_S];
  __shared__ float scores_sm[TILE_S];

  lm_sm[t] = lastm[(size_t)b * NH + t];
  v_sm[t]  = V[t];
  __syncthreads();

  // ---- l[t] = dot(lastm[b,:], W[t,:]) (fp32) ----
  {
    const float4* wrow = (const float4*)(W + (size_t)t * NH);
    const float4* lrow = (const float4*)lm_sm;
    float a0 = 0.f, a1 = 0.f, a2 = 0.f, a3 = 0.f;
#pragma unroll 8
    for (int i = 0; i < NH / 4; ++i) {
      float4 w4 = wrow[i];
      float4 m4 = lrow[i];
      a0 = fmaf(w4.x, m4.x, a0);
      a1 = fmaf(w4.y, m4.y, a1);
      a2 = fmaf(w4.z, m4.z, a2);
      a3 = fmaf(w4.w, m4.w, a3);
    }
    l_sm[t] = (a0 + a1) + (a2 + a3);
  }

  // ---- U B-fragments in registers (verified map from R1) ----
  bf16x8 u_frag[4][8];
#pragma unroll
  for (int nf = 0; nf < 4; ++nf) {
    const int n = wave * 64 + nf * 16 + m16;
    const float* urow = U + (size_t)n * NH;
#pragma unroll
    for (int kk = 0; kk < 8; ++kk) {
      const float4 lo = *(const float4*)(urow + kk * 32 + quad * 8);
      const float4 hi = *(const float4*)(urow + kk * 32 + quad * 8 + 4);
      bf16x8 f;
      f[0] = (__bf16)lo.x; f[1] = (__bf16)lo.y;
      f[2] = (__bf16)lo.z; f[3] = (__bf16)lo.w;
      f[4] = (__bf16)hi.x; f[5] = (__bf16)hi.y;
      f[6] = (__bf16)hi.z; f[7] = (__bf16)hi.w;
      u_frag[nf][kk] = f;
    }
  }

  float m_run  = -INFINITY;
  float Z      = 0.f;
  float pooled = 0.f;   // thread t owns h = t (unnormalized, relative to m_run)

  __syncthreads();      // l_sm ready

  float l_reg[4], v_reg[4];
#pragma unroll
  for (int nf = 0; nf < 4; ++nf) {
    const int n = wave * 64 + nf * 16 + m16;
    l_reg[nf] = l_sm[n];
    v_reg[nf] = v_sm[n];
  }

  for (int tile = 0; tile < ntiles; ++tile) {
    const int s0   = s_begin + tile * TILE_S;
    const int rows = min(TILE_S, s_end - s0);

    // ---- stage fp32 -> bf16 LDS: 4x (2 global float4 -> 1 ds_write_b128) per thread ----
    const float4* src4 = (const float4*)(mem + ((size_t)b * NS + s0) * NH);
#pragma unroll
    for (int i = 0; i < 4; ++i) {
      const int f2  = i * 256 + t;      // 8-float chunk index
      const int row = f2 >> 5;
      const int c8  = (f2 & 31) * 8;
      bf16x8 pk;
      if (row < rows) {
        const float4 a = src4[f2 * 2];
        const float4 c = src4[f2 * 2 + 1];
        pk[0] = (__bf16)a.x; pk[1] = (__bf16)a.y;
        pk[2] = (__bf16)a.z; pk[3] = (__bf16)a.w;
        pk[4] = (__bf16)c.x; pk[5] = (__bf16)c.y;
        pk[6] = (__bf16)c.z; pk[7] = (__bf16)c.w;
      } else {
        pk = (bf16x8)(__bf16)0.f;
      }
      *(bf16x8*)&mem_sm[row][c8] = pk;
    }
    __syncthreads();

    // ---- MFMA: a[s,n] 32 rows x 64 cols per wave ----
    f32x4 acc[2][4];
    const f32x4 fzero = {0.f, 0.f, 0.f, 0.f};
#pragma unroll
    for (int mt = 0; mt < 2; ++mt)
#pragma unroll
      for (int nf = 0; nf < 4; ++nf)
        acc[mt][nf] = fzero;

#pragma unroll
    for (int kk = 0; kk < 8; ++kk) {
      const int c = kk * 32 + quad * 8;
      bf16x8 a0 = *(const bf16x8*)&mem_sm[m16][c];
      bf16x8 a1 = *(const bf16x8*)&mem_sm[16 + m16][c];
#pragma unroll
      for (int nf = 0; nf < 4; ++nf) {
        acc[0][nf] = __builtin_amdgcn_mfma_f32_16x16x32_bf16(a0, u_frag[nf][kk], acc[0][nf], 0, 0, 0);
        acc[1][nf] = __builtin_amdgcn_mfma_f32_16x16x32_bf16(a1, u_frag[nf][kk], acc[1][nf], 0, 0, 0);
      }
    }

    // ---- p = sum_n tanh(a + l[n]) * V[n] over this wave's 64 n ----
    float p[2][4];
#pragma unroll
    for (int mt = 0; mt < 2; ++mt) {
#pragma unroll
      for (int reg = 0; reg < 4; ++reg) {
        float s = 0.f;
#pragma unroll
        for (int nf = 0; nf < 4; ++nf)
          s = fmaf(tanh_fast(acc[mt][nf][reg] + l_reg[nf]), v_reg[nf], s);
        p[mt][reg] = s;
      }
    }
#pragma unroll
    for (int off = 1; off < 16; off <<= 1) {
#pragma unroll
      for (int mt = 0; mt < 2; ++mt)
#pragma unroll
        for (int reg = 0; reg < 4; ++reg)
          p[mt][reg] += __shfl_xor(p[mt][reg], off);
    }
    if (m16 == 0) {
#pragma unroll
      for (int mt = 0; mt < 2; ++mt)
#pragma unroll
        for (int reg = 0; reg < 4; ++reg)
          swave_sm[wave][mt * 16 + quad * 4 + reg] = p[mt][reg];
    }
    __syncthreads();

    if (t < TILE_S)
      scores_sm[t] = swave_sm[0][t] + swave_sm[1][t] + swave_sm[2][t] + swave_sm[3][t];
    __syncthreads();

    // ---- online softmax + pooled update (all threads compute identical m/Z) ----
    float m_tile = -INFINITY;
    for (int r = 0; r < rows; ++r) m_tile = fmaxf(m_tile, scores_sm[r]);
    const float m_new = fmaxf(m_run, m_tile);
    const float fac   = __expf(m_run - m_new);   // exp(-inf)=0 first tile
    float z_t = 0.f, pool_t = 0.f;
    for (int r = 0; r < rows; ++r) {
      const float e = __expf(scores_sm[r] - m_new);
      z_t += e;
      pool_t = fmaf(e, (float)mem_sm[r][t], pool_t);
    }
    Z      = Z * fac + z_t;
    pooled = pooled * fac + pool_t;
    m_run  = m_new;
    __syncthreads();
  }

  // ---- write partial state ----
  float* base = ws + (size_t)blockIdx.x * WS_STRIDE;
  if (t == 0) { base[0] = m_run; base[1] = Z; }
  base[2 + t] = pooled;
}

// ---------------- Kernel 2: merge halves + MetaW projection ----------------
__global__ __launch_bounds__(256, 4)
void merge_project(const float* __restrict__ ws,
                   const float* __restrict__ MetaW,  // [4,H]
                   const float* __restrict__ Metab,  // [4]
                   float* __restrict__ out)          // [B,4]
{
  const int b    = blockIdx.x;
  const int t    = threadIdx.x;
  const int wave = t >> 6;
  const int lane = t & 63;

  __shared__ float pooled_sm[NH];

  const float* b0 = ws + (size_t)(b * 2)     * WS_STRIDE;
  const float* b1 = ws + (size_t)(b * 2 + 1) * WS_STRIDE;
  const float m0 = b0[0], Z0 = b0[1];
  const float m1 = b1[0], Z1 = b1[1];
  const float mm = fmaxf(m0, m1);
  const float w0 = __expf(m0 - mm);
  const float w1 = __expf(m1 - mm);
  const float Zi = 1.f / (Z0 * w0 + Z1 * w1);

  pooled_sm[t] = (b0[2 + t] * w0 + b1[2 + t] * w1) * Zi;
  __syncthreads();

  float s = 0.f;
#pragma unroll
  for (int i = 0; i < 4; ++i) {
    const int h = i * 64 + lane;
    s = fmaf(pooled_sm[h], MetaW[(size_t)wave * NH + h], s);
  }
#pragma unroll
  for (int off = 32; off > 0; off >>= 1)
    s += __shfl_down(s, off);
  if (lane == 0)
    out[b * 4 + wave] = s + Metab[wave];
}

extern "C" void kernel_launch(void* const* d_in, const int* in_sizes, int n_in,
                              void* d_out, int out_size, void* d_ws, size_t ws_size,
                              hipStream_t stream) {
  const float* mem   = (const float*)d_in[0];
  const float* lastm = (const float*)d_in[1];
  const float* U     = (const float*)d_in[2];
  const float* W     = (const float*)d_in[3];
  const float* V     = (const float*)d_in[4];
  const float* MetaW = (const float*)d_in[5];
  const float* Metab = (const float*)d_in[6];
  float* out = (float*)d_out;
  float* ws  = (float*)d_ws;   // needs NB*2*WS_STRIDE*4 = ~1.06 MB

  hipLaunchKernelGGL(fused_meta_attn_part, dim3(NB * 2), dim3(256), 0, stream,
                     mem, lastm, U, W, V, ws);
  hipLaunchKernelGGL(merge_project, dim3(NB), dim3(256), 0, stream,
                     ws, MetaW, Metab, out);
}

// Round 3
// 270.804 us; speedup vs baseline: 1.1177x; 1.1177x over previous
//
#include <hip/hip_runtime.h>
#include <hip/hip_bf16.h>
#include <math.h>

#define NB 512
#define NS 200
#define NH 256
#define TILE_S 32
#define LDSPAD 8
#define LDW (NH + LDSPAD)        // 264 bf16 row stride
#define WS_STRIDE 258            // per (b,half): [m, Z, pooled[256]]
#define NPART (NB * 2)           // 1024 partial blocks

// ws float-offset layout
#define OFF_PART 0
#define OFF_L    (NPART * WS_STRIDE)           // 264192 floats
#define OFF_UB   (OFF_L + NB * NH)             // 395264 floats (U as bf16 = 32768 floats)
#define WS_FLOATS_PRE  (OFF_UB + (NH * NH) / 2)   // 428032 floats = 1.71 MB
#define WS_FLOATS_MIN  (NPART * WS_STRIDE)        // 1.06 MB (proven in R2)

typedef __bf16 bf16x8 __attribute__((ext_vector_type(8)));
typedef float  f32x4  __attribute__((ext_vector_type(4)));

__device__ __forceinline__ float tanh_fast(float x) {
  float xc = fminf(fmaxf(x, -10.f), 10.f);
  float e  = __expf(2.f * xc);
  return (e - 1.f) / (e + 1.f);
}

// ---------------- Kernel 0: precompute l = lastm@W^T (fp32) and U -> bf16 ----
__global__ __launch_bounds__(256)
void precompute(const float* __restrict__ lastm, const float* __restrict__ W,
                const float* __restrict__ U,
                float* __restrict__ l_ws, __bf16* __restrict__ Ubf)
{
  const int t = threadIdx.x;
  if (blockIdx.x < NB) {
    const int b = blockIdx.x;
    __shared__ float lm_sm[NH];
    lm_sm[t] = lastm[(size_t)b * NH + t];
    __syncthreads();
    const float4* wrow = (const float4*)(W + (size_t)t * NH);
    const float4* lrow = (const float4*)lm_sm;
    float a0 = 0.f, a1 = 0.f, a2 = 0.f, a3 = 0.f;
#pragma unroll 8
    for (int i = 0; i < NH / 4; ++i) {
      float4 w4 = wrow[i];
      float4 m4 = lrow[i];
      a0 = fmaf(w4.x, m4.x, a0);
      a1 = fmaf(w4.y, m4.y, a1);
      a2 = fmaf(w4.z, m4.z, a2);
      a3 = fmaf(w4.w, m4.w, a3);
    }
    l_ws[(size_t)b * NH + t] = (a0 + a1) + (a2 + a3);
  } else {
    // U fp32 -> bf16: 32 blocks x 256 threads x 8 elems = 65536
    const int i = (blockIdx.x - NB) * (256 * 8) + t * 8;
    const float4* s = (const float4*)(U + i);
    const float4 a = s[0], c = s[1];
    bf16x8 pk;
    pk[0] = (__bf16)a.x; pk[1] = (__bf16)a.y;
    pk[2] = (__bf16)a.z; pk[3] = (__bf16)a.w;
    pk[4] = (__bf16)c.x; pk[5] = (__bf16)c.y;
    pk[6] = (__bf16)c.z; pk[7] = (__bf16)c.w;
    *(bf16x8*)(Ubf + i) = pk;
  }
}

// ---------------- Kernel 1: partial attention over an S-range ----------------
// grid = 1024: block (b, half). half 0 -> s in [0,96), half 1 -> s in [96,200).
// PRE: l and bf16-U precomputed in ws (fast path). !PRE: self-contained fallback.
template<bool PRE>
__global__ __launch_bounds__(256, 4)
void fused_meta_attn_part(const float* __restrict__ mem,    // [B,S,H]
                          const float* __restrict__ lastm,  // [B,H]
                          const float* __restrict__ U,      // [H,H] fp32
                          const float* __restrict__ W,      // [H,H]
                          const float* __restrict__ V,      // [H]
                          const float* __restrict__ l_ws,   // [B,H] (PRE)
                          const __bf16* __restrict__ Ubf,   // [H,H] bf16 (PRE)
                          float* __restrict__ part)         // [NPART, WS_STRIDE]
{
  const int b    = blockIdx.x >> 1;
  const int half = blockIdx.x & 1;
  const int s_begin = half ? 96 : 0;
  const int s_end   = half ? NS : 96;
  const int ntiles  = half ? 4 : 3;

  const int t    = threadIdx.x;   // 0..255
  const int wave = t >> 6;        // owns n-cols [wave*64, wave*64+64)
  const int lane = t & 63;
  const int m16  = lane & 15;
  const int quad = lane >> 4;

  __shared__ __align__(16) __bf16 mem_sm[TILE_S][LDW];  // 16.9 KB
  __shared__ float swave_sm[4][TILE_S];
  __shared__ float scores_sm[TILE_S];
  __shared__ float l_fallback_sm[NH];   // only used by !PRE
  __shared__ float lm_sm[NH];           // only used by !PRE

  if (!PRE) {
    lm_sm[t] = lastm[(size_t)b * NH + t];
    __syncthreads();
    const float4* wrow = (const float4*)(W + (size_t)t * NH);
    const float4* lrow = (const float4*)lm_sm;
    float a0 = 0.f, a1 = 0.f, a2 = 0.f, a3 = 0.f;
#pragma unroll 8
    for (int i = 0; i < NH / 4; ++i) {
      float4 w4 = wrow[i];
      float4 m4 = lrow[i];
      a0 = fmaf(w4.x, m4.x, a0);
      a1 = fmaf(w4.y, m4.y, a1);
      a2 = fmaf(w4.z, m4.z, a2);
      a3 = fmaf(w4.w, m4.w, a3);
    }
    l_fallback_sm[t] = (a0 + a1) + (a2 + a3);
    __syncthreads();
  }

  // per-thread l/V for this wave's 4 n-fragments
  float l_reg[4], v_reg[4];
#pragma unroll
  for (int nf = 0; nf < 4; ++nf) {
    const int n = wave * 64 + nf * 16 + m16;
    l_reg[nf] = PRE ? l_ws[(size_t)b * NH + n] : l_fallback_sm[n];
    v_reg[nf] = V[n];
  }

  float m_run  = -INFINITY;
  float Z      = 0.f;
  float pooled = 0.f;   // thread t owns h = t (unnormalized, relative to m_run)

  for (int tile = 0; tile < ntiles; ++tile) {
    const int s0   = s_begin + tile * TILE_S;
    const int rows = min(TILE_S, s_end - s0);

    // ---- stage fp32 -> bf16 LDS ----
    const float4* src4 = (const float4*)(mem + ((size_t)b * NS + s0) * NH);
#pragma unroll
    for (int i = 0; i < 4; ++i) {
      const int f2  = i * 256 + t;
      const int row = f2 >> 5;
      const int c8  = (f2 & 31) * 8;
      bf16x8 pk;
      if (row < rows) {
        const float4 a = src4[f2 * 2];
        const float4 c = src4[f2 * 2 + 1];
        pk[0] = (__bf16)a.x; pk[1] = (__bf16)a.y;
        pk[2] = (__bf16)a.z; pk[3] = (__bf16)a.w;
        pk[4] = (__bf16)c.x; pk[5] = (__bf16)c.y;
        pk[6] = (__bf16)c.z; pk[7] = (__bf16)c.w;
      } else {
        pk = (bf16x8)(__bf16)0.f;
      }
      *(bf16x8*)&mem_sm[row][c8] = pk;
    }
    __syncthreads();

    // ---- MFMA: a[s,n] 32 rows x 64 cols per wave; B-frags streamed from L2 ----
    f32x4 acc[2][4];
    const f32x4 fzero = {0.f, 0.f, 0.f, 0.f};
#pragma unroll
    for (int mt = 0; mt < 2; ++mt)
#pragma unroll
      for (int nf = 0; nf < 4; ++nf)
        acc[mt][nf] = fzero;

#pragma unroll
    for (int kk = 0; kk < 8; ++kk) {
      const int c = kk * 32 + quad * 8;
      bf16x8 a0 = *(const bf16x8*)&mem_sm[m16][c];
      bf16x8 a1 = *(const bf16x8*)&mem_sm[16 + m16][c];
#pragma unroll
      for (int nf = 0; nf < 4; ++nf) {
        const int n = wave * 64 + nf * 16 + m16;
        bf16x8 bf;
        if (PRE) {
          bf = *(const bf16x8*)(Ubf + ((size_t)n << 8) + c);
        } else {
          const float* urow = U + ((size_t)n << 8) + c;
          const float4 lo = *(const float4*)urow;
          const float4 hi = *(const float4*)(urow + 4);
          bf[0] = (__bf16)lo.x; bf[1] = (__bf16)lo.y;
          bf[2] = (__bf16)lo.z; bf[3] = (__bf16)lo.w;
          bf[4] = (__bf16)hi.x; bf[5] = (__bf16)hi.y;
          bf[6] = (__bf16)hi.z; bf[7] = (__bf16)hi.w;
        }
        acc[0][nf] = __builtin_amdgcn_mfma_f32_16x16x32_bf16(a0, bf, acc[0][nf], 0, 0, 0);
        acc[1][nf] = __builtin_amdgcn_mfma_f32_16x16x32_bf16(a1, bf, acc[1][nf], 0, 0, 0);
      }
    }

    // ---- p = sum_n tanh(a + l[n]) * V[n] over this wave's 64 n ----
    float p[2][4];
#pragma unroll
    for (int mt = 0; mt < 2; ++mt) {
#pragma unroll
      for (int reg = 0; reg < 4; ++reg) {
        float s = 0.f;
#pragma unroll
        for (int nf = 0; nf < 4; ++nf)
          s = fmaf(tanh_fast(acc[mt][nf][reg] + l_reg[nf]), v_reg[nf], s);
        p[mt][reg] = s;
      }
    }
#pragma unroll
    for (int off = 1; off < 16; off <<= 1) {
#pragma unroll
      for (int mt = 0; mt < 2; ++mt)
#pragma unroll
        for (int reg = 0; reg < 4; ++reg)
          p[mt][reg] += __shfl_xor(p[mt][reg], off);
    }
    if (m16 == 0) {
#pragma unroll
      for (int mt = 0; mt < 2; ++mt)
#pragma unroll
        for (int reg = 0; reg < 4; ++reg)
          swave_sm[wave][mt * 16 + quad * 4 + reg] = p[mt][reg];
    }
    __syncthreads();

    if (t < TILE_S)
      scores_sm[t] = swave_sm[0][t] + swave_sm[1][t] + swave_sm[2][t] + swave_sm[3][t];
    __syncthreads();

    // ---- online softmax + pooled update ----
    float m_tile = -INFINITY;
    for (int r = 0; r < rows; ++r) m_tile = fmaxf(m_tile, scores_sm[r]);
    const float m_new = fmaxf(m_run, m_tile);
    const float fac   = __expf(m_run - m_new);
    float z_t = 0.f, pool_t = 0.f;
    for (int r = 0; r < rows; ++r) {
      const float e = __expf(scores_sm[r] - m_new);
      z_t += e;
      pool_t = fmaf(e, (float)mem_sm[r][t], pool_t);
    }
    Z      = Z * fac + z_t;
    pooled = pooled * fac + pool_t;
    m_run  = m_new;
    __syncthreads();
  }

  float* base = part + (size_t)blockIdx.x * WS_STRIDE;
  if (t == 0) { base[0] = m_run; base[1] = Z; }
  base[2 + t] = pooled;
}

// ---------------- Kernel 2: merge halves + MetaW projection ----------------
__global__ __launch_bounds__(256, 4)
void merge_project(const float* __restrict__ part,
                   const float* __restrict__ MetaW,  // [4,H]
                   const float* __restrict__ Metab,  // [4]
                   float* __restrict__ out)          // [B,4]
{
  const int b    = blockIdx.x;
  const int t    = threadIdx.x;
  const int wave = t >> 6;
  const int lane = t & 63;

  __shared__ float pooled_sm[NH];

  const float* b0 = part + (size_t)(b * 2)     * WS_STRIDE;
  const float* b1 = part + (size_t)(b * 2 + 1) * WS_STRIDE;
  const float m0 = b0[0], Z0 = b0[1];
  const float m1 = b1[0], Z1 = b1[1];
  const float mm = fmaxf(m0, m1);
  const float w0 = __expf(m0 - mm);
  const float w1 = __expf(m1 - mm);
  const float Zi = 1.f / (Z0 * w0 + Z1 * w1);

  pooled_sm[t] = (b0[2 + t] * w0 + b1[2 + t] * w1) * Zi;
  __syncthreads();

  float s = 0.f;
#pragma unroll
  for (int i = 0; i < 4; ++i) {
    const int h = i * 64 + lane;
    s = fmaf(pooled_sm[h], MetaW[(size_t)wave * NH + h], s);
  }
#pragma unroll
  for (int off = 32; off > 0; off >>= 1)
    s += __shfl_down(s, off);
  if (lane == 0)
    out[b * 4 + wave] = s + Metab[wave];
}

extern "C" void kernel_launch(void* const* d_in, const int* in_sizes, int n_in,
                              void* d_out, int out_size, void* d_ws, size_t ws_size,
                              hipStream_t stream) {
  const float* mem   = (const float*)d_in[0];
  const float* lastm = (const float*)d_in[1];
  const float* U     = (const float*)d_in[2];
  const float* W     = (const float*)d_in[3];
  const float* V     = (const float*)d_in[4];
  const float* MetaW = (const float*)d_in[5];
  const float* Metab = (const float*)d_in[6];
  float* out = (float*)d_out;
  float* ws  = (float*)d_ws;

  float* part = ws + OFF_PART;

  if (ws_size >= (size_t)WS_FLOATS_PRE * sizeof(float)) {
    float*  l_ws = ws + OFF_L;
    __bf16* Ubf  = (__bf16*)(ws + OFF_UB);
    hipLaunchKernelGGL(precompute, dim3(NB + 32), dim3(256), 0, stream,
                       lastm, W, U, l_ws, Ubf);
    hipLaunchKernelGGL(fused_meta_attn_part<true>, dim3(NPART), dim3(256), 0, stream,
                       mem, lastm, U, W, V, l_ws, Ubf, part);
  } else {
    hipLaunchKernelGGL(fused_meta_attn_part<false>, dim3(NPART), dim3(256), 0, stream,
                       mem, lastm, U, W, V, (const float*)nullptr, (const __bf16*)nullptr, part);
  }
  hipLaunchKernelGGL(merge_project, dim3(NB), dim3(256), 0, stream,
                     part, MetaW, Metab, out);
}

// Round 4
// 265.736 us; speedup vs baseline: 1.1390x; 1.0191x over previous
//
#include <hip/hip_runtime.h>
#include <hip/hip_bf16.h>
#include <math.h>

#define NB 512
#define NS 200
#define NH 256
#define TILE_S 32
#define LDSPAD 8
#define LDW (NH + LDSPAD)        // 264 bf16 row stride
#define WS_STRIDE 258            // per (b,half): [m, Z, pooled[256]]
#define NPART (NB * 2)           // 1024 partial blocks

// ws float-offset layout
#define OFF_PART 0
#define OFF_L    (NPART * WS_STRIDE)              // partials: 1024*258 floats
#define OFF_UB   (OFF_L + NB * NH)                // l: 512*256 floats
#define WS_FLOATS_PRE  (OFF_UB + (NH * NH) / 2)   // + U-bf16 swizzled (32768 floats) = 1.71 MB

typedef __bf16 bf16x8 __attribute__((ext_vector_type(8)));
typedef float  f32x4  __attribute__((ext_vector_type(4)));

__device__ __forceinline__ float tanh_fast(float x) {
  float xc = fminf(fmaxf(x, -10.f), 10.f);
  float e  = __expf(2.f * xc);
  return (e - 1.f) / (e + 1.f);
}

// ---------------- Kernel 0: precompute l = lastm@W^T (fp32) and swizzled bf16 U ----
// Uswz layout: frag id = ((n_blk*8 + kk)*64 + lane), 8 bf16 each.
// frag contents: U[n_blk*16 + (lane&15)][kk*32 + (lane>>4)*8 + j], j=0..7
__global__ __launch_bounds__(256)
void precompute(const float* __restrict__ lastm, const float* __restrict__ W,
                const float* __restrict__ U,
                float* __restrict__ l_ws, __bf16* __restrict__ Uswz)
{
  const int t = threadIdx.x;
  if (blockIdx.x < NB) {
    const int b = blockIdx.x;
    __shared__ float lm_sm[NH];
    lm_sm[t] = lastm[(size_t)b * NH + t];
    __syncthreads();
    const float4* wrow = (const float4*)(W + (size_t)t * NH);
    const float4* lrow = (const float4*)lm_sm;
    float a0 = 0.f, a1 = 0.f, a2 = 0.f, a3 = 0.f;
#pragma unroll 8
    for (int i = 0; i < NH / 4; ++i) {
      float4 w4 = wrow[i];
      float4 m4 = lrow[i];
      a0 = fmaf(w4.x, m4.x, a0);
      a1 = fmaf(w4.y, m4.y, a1);
      a2 = fmaf(w4.z, m4.z, a2);
      a3 = fmaf(w4.w, m4.w, a3);
    }
    l_ws[(size_t)b * NH + t] = (a0 + a1) + (a2 + a3);
  } else {
    // 32 blocks x 256 threads = 8192 frags, one 16B frag per thread
    const int id    = (blockIdx.x - NB) * 256 + t;
    const int n_blk = id >> 9;
    const int kk    = (id >> 6) & 7;
    const int lane  = id & 63;
    const int row   = n_blk * 16 + (lane & 15);
    const int col   = kk * 32 + (lane >> 4) * 8;
    const float4* s = (const float4*)(U + (size_t)row * NH + col);
    const float4 a = s[0], c = s[1];
    bf16x8 pk;
    pk[0] = (__bf16)a.x; pk[1] = (__bf16)a.y;
    pk[2] = (__bf16)a.z; pk[3] = (__bf16)a.w;
    pk[4] = (__bf16)c.x; pk[5] = (__bf16)c.y;
    pk[6] = (__bf16)c.z; pk[7] = (__bf16)c.w;
    *(bf16x8*)(Uswz + (size_t)id * 8) = pk;
  }
}

// ---------------- Kernel 1: partial attention over an S-range ----------------
// grid = 1024: block (b, half). half 0 -> s in [0,96), half 1 -> s in [96,200).
template<bool PRE>
__attribute__((amdgpu_waves_per_eu(4, 4)))   // pin allocator at 4 waves/EU (<=128 regs), forbid squeeze-to-64+spill
__global__ void __launch_bounds__(256)
fused_meta_attn_part(const float* __restrict__ mem,    // [B,S,H]
                     const float* __restrict__ lastm,  // [B,H]
                     const float* __restrict__ U,      // [H,H] fp32 (fallback)
                     const float* __restrict__ W,      // [H,H] (fallback)
                     const float* __restrict__ V,      // [H]
                     const float* __restrict__ l_ws,   // [B,H] (PRE)
                     const __bf16* __restrict__ Uswz,  // swizzled bf16 U (PRE)
                     float* __restrict__ part)         // [NPART, WS_STRIDE]
{
  const int b    = blockIdx.x >> 1;
  const int half = blockIdx.x & 1;
  const int s_begin = half ? 96 : 0;
  const int s_end   = half ? NS : 96;
  const int ntiles  = half ? 4 : 3;

  const int t    = threadIdx.x;   // 0..255
  const int wave = t >> 6;        // owns n-cols [wave*64, wave*64+64)
  const int lane = t & 63;
  const int m16  = lane & 15;
  const int quad = lane >> 4;

  __shared__ __align__(16) __bf16 mem_sm[TILE_S][LDW];  // 16.9 KB
  __shared__ float swave_sm[4][TILE_S];
  __shared__ float scores_sm[TILE_S];
  __shared__ float l_fallback_sm[NH];   // only used by !PRE
  __shared__ float lm_sm[NH];           // only used by !PRE

  if (!PRE) {
    lm_sm[t] = lastm[(size_t)b * NH + t];
    __syncthreads();
    const float4* wrow = (const float4*)(W + (size_t)t * NH);
    const float4* lrow = (const float4*)lm_sm;
    float a0 = 0.f, a1 = 0.f, a2 = 0.f, a3 = 0.f;
#pragma unroll 8
    for (int i = 0; i < NH / 4; ++i) {
      float4 w4 = wrow[i];
      float4 m4 = lrow[i];
      a0 = fmaf(w4.x, m4.x, a0);
      a1 = fmaf(w4.y, m4.y, a1);
      a2 = fmaf(w4.z, m4.z, a2);
      a3 = fmaf(w4.w, m4.w, a3);
    }
    l_fallback_sm[t] = (a0 + a1) + (a2 + a3);
    __syncthreads();
  }

  // per-thread l/V for this wave's 4 n-fragments
  float l_reg[4], v_reg[4];
#pragma unroll
  for (int nf = 0; nf < 4; ++nf) {
    const int n = wave * 64 + nf * 16 + m16;
    l_reg[nf] = PRE ? l_ws[(size_t)b * NH + n] : l_fallback_sm[n];
    v_reg[nf] = V[n];
  }

  // this wave's linear U-frag base: frag id = ((wave*4+nf)*8 + kk)*64 + lane
  const __bf16* uw = PRE ? (Uswz + ((size_t)((wave * 4) * 8 * 64) + lane) * 8) : nullptr;

  float m_run  = -INFINITY;
  float Z      = 0.f;
  float pooled = 0.f;   // thread t owns h = t (unnormalized, relative to m_run)

  for (int tile = 0; tile < ntiles; ++tile) {
    const int s0   = s_begin + tile * TILE_S;
    const int rows = min(TILE_S, s_end - s0);

    // ---- stage fp32 -> bf16 LDS; mem is read-once -> nontemporal (protect L2-resident U) ----
    const f32x4* src4 = (const f32x4*)(mem + ((size_t)b * NS + s0) * NH);
#pragma unroll
    for (int i = 0; i < 4; ++i) {
      const int f2  = i * 256 + t;
      const int row = f2 >> 5;
      const int c8  = (f2 & 31) * 8;
      bf16x8 pk;
      if (row < rows) {
        const f32x4 a = __builtin_nontemporal_load(src4 + (size_t)f2 * 2);
        const f32x4 c = __builtin_nontemporal_load(src4 + (size_t)f2 * 2 + 1);
        pk[0] = (__bf16)a[0]; pk[1] = (__bf16)a[1];
        pk[2] = (__bf16)a[2]; pk[3] = (__bf16)a[3];
        pk[4] = (__bf16)c[0]; pk[5] = (__bf16)c[1];
        pk[6] = (__bf16)c[2]; pk[7] = (__bf16)c[3];
      } else {
        pk = (bf16x8)(__bf16)0.f;
      }
      *(bf16x8*)&mem_sm[row][c8] = pk;
    }
    __syncthreads();

    // ---- MFMA: a[s,n] 32 rows x 64 cols per wave; B-frags streamed from L2 ----
    f32x4 acc[2][4];
    const f32x4 fzero = {0.f, 0.f, 0.f, 0.f};
#pragma unroll
    for (int mt = 0; mt < 2; ++mt)
#pragma unroll
      for (int nf = 0; nf < 4; ++nf)
        acc[mt][nf] = fzero;

#pragma unroll
    for (int kk = 0; kk < 8; ++kk) {
      const int c = kk * 32 + quad * 8;
      bf16x8 a0 = *(const bf16x8*)&mem_sm[m16][c];
      bf16x8 a1 = *(const bf16x8*)&mem_sm[16 + m16][c];
#pragma unroll
      for (int nf = 0; nf < 4; ++nf) {
        bf16x8 bf;
        if (PRE) {
          bf = *(const bf16x8*)(uw + (size_t)((nf * 8 + kk) << 9));  // 512 elems = 1KB per frag step
        } else {
          const int n = wave * 64 + nf * 16 + m16;
          const float* urow = U + ((size_t)n << 8) + c;
          const float4 lo = *(const float4*)urow;
          const float4 hi = *(const float4*)(urow + 4);
          bf[0] = (__bf16)lo.x; bf[1] = (__bf16)lo.y;
          bf[2] = (__bf16)lo.z; bf[3] = (__bf16)lo.w;
          bf[4] = (__bf16)hi.x; bf[5] = (__bf16)hi.y;
          bf[6] = (__bf16)hi.z; bf[7] = (__bf16)hi.w;
        }
        acc[0][nf] = __builtin_amdgcn_mfma_f32_16x16x32_bf16(a0, bf, acc[0][nf], 0, 0, 0);
        acc[1][nf] = __builtin_amdgcn_mfma_f32_16x16x32_bf16(a1, bf, acc[1][nf], 0, 0, 0);
      }
    }

    // ---- p = sum_n tanh(a + l[n]) * V[n] over this wave's 64 n ----
    float p[2][4];
#pragma unroll
    for (int mt = 0; mt < 2; ++mt) {
#pragma unroll
      for (int reg = 0; reg < 4; ++reg) {
        float s = 0.f;
#pragma unroll
        for (int nf = 0; nf < 4; ++nf)
          s = fmaf(tanh_fast(acc[mt][nf][reg] + l_reg[nf]), v_reg[nf], s);
        p[mt][reg] = s;
      }
    }
#pragma unroll
    for (int off = 1; off < 16; off <<= 1) {
#pragma unroll
      for (int mt = 0; mt < 2; ++mt)
#pragma unroll
        for (int reg = 0; reg < 4; ++reg)
          p[mt][reg] += __shfl_xor(p[mt][reg], off);
    }
    if (m16 == 0) {
#pragma unroll
      for (int mt = 0; mt < 2; ++mt)
#pragma unroll
        for (int reg = 0; reg < 4; ++reg)
          swave_sm[wave][mt * 16 + quad * 4 + reg] = p[mt][reg];
    }
    __syncthreads();

    if (t < TILE_S)
      scores_sm[t] = swave_sm[0][t] + swave_sm[1][t] + swave_sm[2][t] + swave_sm[3][t];
    __syncthreads();

    // ---- online softmax + pooled update (all threads compute identical m/Z) ----
    float m_tile = -INFINITY;
    for (int r = 0; r < rows; ++r) m_tile = fmaxf(m_tile, scores_sm[r]);
    const float m_new = fmaxf(m_run, m_tile);
    const float fac   = __expf(m_run - m_new);
    float z_t = 0.f, pool_t = 0.f;
    for (int r = 0; r < rows; ++r) {
      const float e = __expf(scores_sm[r] - m_new);
      z_t += e;
      pool_t = fmaf(e, (float)mem_sm[r][t], pool_t);
    }
    Z      = Z * fac + z_t;
    pooled = pooled * fac + pool_t;
    m_run  = m_new;
    __syncthreads();
  }

  float* base = part + (size_t)blockIdx.x * WS_STRIDE;
  if (t == 0) { base[0] = m_run; base[1] = Z; }
  base[2 + t] = pooled;
}

// ---------------- Kernel 2: merge halves + MetaW projection ----------------
__global__ __launch_bounds__(256)
void merge_project(const float* __restrict__ part,
                   const float* __restrict__ MetaW,  // [4,H]
                   const float* __restrict__ Metab,  // [4]
                   float* __restrict__ out)          // [B,4]
{
  const int b    = blockIdx.x;
  const int t    = threadIdx.x;
  const int wave = t >> 6;
  const int lane = t & 63;

  __shared__ float pooled_sm[NH];

  const float* b0 = part + (size_t)(b * 2)     * WS_STRIDE;
  const float* b1 = part + (size_t)(b * 2 + 1) * WS_STRIDE;
  const float m0 = b0[0], Z0 = b0[1];
  const float m1 = b1[0], Z1 = b1[1];
  const float mm = fmaxf(m0, m1);
  const float w0 = __expf(m0 - mm);
  const float w1 = __expf(m1 - mm);
  const float Zi = 1.f / (Z0 * w0 + Z1 * w1);

  pooled_sm[t] = (b0[2 + t] * w0 + b1[2 + t] * w1) * Zi;
  __syncthreads();

  float s = 0.f;
#pragma unroll
  for (int i = 0; i < 4; ++i) {
    const int h = i * 64 + lane;
    s = fmaf(pooled_sm[h], MetaW[(size_t)wave * NH + h], s);
  }
#pragma unroll
  for (int off = 32; off > 0; off >>= 1)
    s += __shfl_down(s, off);
  if (lane == 0)
    out[b * 4 + wave] = s + Metab[wave];
}

extern "C" void kernel_launch(void* const* d_in, const int* in_sizes, int n_in,
                              void* d_out, int out_size, void* d_ws, size_t ws_size,
                              hipStream_t stream) {
  const float* mem   = (const float*)d_in[0];
  const float* lastm = (const float*)d_in[1];
  const float* U     = (const float*)d_in[2];
  const float* W     = (const float*)d_in[3];
  const float* V     = (const float*)d_in[4];
  const float* MetaW = (const float*)d_in[5];
  const float* Metab = (const float*)d_in[6];
  float* out = (float*)d_out;
  float* ws  = (float*)d_ws;

  float* part = ws + OFF_PART;

  if (ws_size >= (size_t)WS_FLOATS_PRE * sizeof(float)) {
    float*  l_ws = ws + OFF_L;
    __bf16* Uswz = (__bf16*)(ws + OFF_UB);
    hipLaunchKernelGGL(precompute, dim3(NB + 32), dim3(256), 0, stream,
                       lastm, W, U, l_ws, Uswz);
    hipLaunchKernelGGL(fused_meta_attn_part<true>, dim3(NPART), dim3(256), 0, stream,
                       mem, lastm, U, W, V, l_ws, Uswz, part);
  } else {
    hipLaunchKernelGGL(fused_meta_attn_part<false>, dim3(NPART), dim3(256), 0, stream,
                       mem, lastm, U, W, V, (const float*)nullptr, (const __bf16*)nullptr, part);
  }
  hipLaunchKernelGGL(merge_project, dim3(NB), dim3(256), 0, stream,
                     part, MetaW, Metab, out);
}

// Round 5
// 211.744 us; speedup vs baseline: 1.4294x; 1.2550x over previous
//
#include <hip/hip_runtime.h>
#include <hip/hip_bf16.h>
#include <math.h>

#define NB 512
#define NS 200
#define NH 256
#define TILE_S 32
#define LDSPAD 8
#define LDW (NH + LDSPAD)        // 264 bf16 row stride: 528B rows -> 2-way bank aliasing only (free)
#define WS_STRIDE 258            // per (b,half): [m, Z, pooled[256]]
#define NPART (NB * 2)           // 1024 partial blocks

// ws float-offset layout
#define OFF_PART 0
#define OFF_L    (NPART * WS_STRIDE)              // partials: 1024*258 floats
#define OFF_UB   (OFF_L + NB * NH)                // l: 512*256 floats
#define WS_FLOATS_PRE  (OFF_UB + (NH * NH) / 2)   // + U-bf16 swizzled (32768 floats) = 1.71 MB

typedef __bf16 bf16x8 __attribute__((ext_vector_type(8)));
typedef float  f32x4  __attribute__((ext_vector_type(4)));

__device__ __forceinline__ float tanh_fast(float x) {
  float xc = fminf(fmaxf(x, -10.f), 10.f);
  float e  = __expf(2.f * xc);
  return (e - 1.f) / (e + 1.f);
}

// ---------------- Kernel 0: precompute l = lastm@W^T (fp32) and swizzled bf16 U ----
// Uswz frag id = ((n_blk*8 + kk)*64 + lane), 8 bf16 each:
// contents U[n_blk*16 + (lane&15)][kk*32 + (lane>>4)*8 + j], j=0..7
__global__ __launch_bounds__(256)
void precompute(const float* __restrict__ lastm, const float* __restrict__ W,
                const float* __restrict__ U,
                float* __restrict__ l_ws, __bf16* __restrict__ Uswz)
{
  const int t = threadIdx.x;
  if (blockIdx.x < NB) {
    const int b = blockIdx.x;
    __shared__ float lm_sm[NH];
    lm_sm[t] = lastm[(size_t)b * NH + t];
    __syncthreads();
    const float4* wrow = (const float4*)(W + (size_t)t * NH);
    const float4* lrow = (const float4*)lm_sm;
    float a0 = 0.f, a1 = 0.f, a2 = 0.f, a3 = 0.f;
#pragma unroll 8
    for (int i = 0; i < NH / 4; ++i) {
      float4 w4 = wrow[i];
      float4 m4 = lrow[i];
      a0 = fmaf(w4.x, m4.x, a0);
      a1 = fmaf(w4.y, m4.y, a1);
      a2 = fmaf(w4.z, m4.z, a2);
      a3 = fmaf(w4.w, m4.w, a3);
    }
    l_ws[(size_t)b * NH + t] = (a0 + a1) + (a2 + a3);
  } else {
    const int id    = (blockIdx.x - NB) * 256 + t;   // 8192 frags
    const int n_blk = id >> 9;
    const int kk    = (id >> 6) & 7;
    const int lane  = id & 63;
    const int row   = n_blk * 16 + (lane & 15);
    const int col   = kk * 32 + (lane >> 4) * 8;
    const float4* s = (const float4*)(U + (size_t)row * NH + col);
    const float4 a = s[0], c = s[1];
    bf16x8 pk;
    pk[0] = (__bf16)a.x; pk[1] = (__bf16)a.y;
    pk[2] = (__bf16)a.z; pk[3] = (__bf16)a.w;
    pk[4] = (__bf16)c.x; pk[5] = (__bf16)c.y;
    pk[6] = (__bf16)c.z; pk[7] = (__bf16)c.w;
    *(bf16x8*)(Uswz + (size_t)id * 8) = pk;
  }
}

// ---------------- Kernel 1: partial attention over an S-range ----------------
// grid = 1024: block (b, half). half 0 -> s in [0,96), half 1 -> s in [96,200).
// __launch_bounds__(256,2): R1-proven codegen (VGPR=128, u_frag in regs, NO scratch
// spill). VGPR=128 still permits 4 waves/EU at runtime -> 4 blocks/CU for grid 1024.
// Do NOT request min 4 waves/EU: R2-R4 proved that squeezes VGPR to 64 and spills
// the accumulators around every staging barrier (94 MB/dispatch of scratch traffic).
template<bool PRE>
__global__ __launch_bounds__(256, 2)
void fused_meta_attn_part(const float* __restrict__ mem,    // [B,S,H]
                          const float* __restrict__ lastm,  // [B,H]
                          const float* __restrict__ U,      // [H,H] fp32 (fallback)
                          const float* __restrict__ W,      // [H,H] (fallback)
                          const float* __restrict__ V,      // [H]
                          const float* __restrict__ l_ws,   // [B,H] (PRE)
                          const __bf16* __restrict__ Uswz,  // swizzled bf16 U (PRE)
                          float* __restrict__ part)         // [NPART, WS_STRIDE]
{
  const int b    = blockIdx.x >> 1;
  const int half = blockIdx.x & 1;
  const int s_begin = half ? 96 : 0;
  const int s_end   = half ? NS : 96;
  const int ntiles  = half ? 4 : 3;

  const int t    = threadIdx.x;   // 0..255
  const int wave = t >> 6;        // owns n-cols [wave*64, wave*64+64)
  const int lane = t & 63;
  const int m16  = lane & 15;
  const int quad = lane >> 4;

  __shared__ __align__(16) __bf16 mem_sm[TILE_S][LDW];  // 16.9 KB
  __shared__ float swave_sm[4][TILE_S];
  __shared__ float scores_sm[TILE_S];
  __shared__ float l_sm[NH];      // fallback only
  __shared__ float lm_sm[NH];     // fallback only

  if (!PRE) {
    lm_sm[t] = lastm[(size_t)b * NH + t];
    __syncthreads();
    const float4* wrow = (const float4*)(W + (size_t)t * NH);
    const float4* lrow = (const float4*)lm_sm;
    float a0 = 0.f, a1 = 0.f, a2 = 0.f, a3 = 0.f;
#pragma unroll 8
    for (int i = 0; i < NH / 4; ++i) {
      float4 w4 = wrow[i];
      float4 m4 = lrow[i];
      a0 = fmaf(w4.x, m4.x, a0);
      a1 = fmaf(w4.y, m4.y, a1);
      a2 = fmaf(w4.z, m4.z, a2);
      a3 = fmaf(w4.w, m4.w, a3);
    }
    l_sm[t] = (a0 + a1) + (a2 + a3);
    __syncthreads();
  }

  // per-thread l/V for this wave's 4 n-fragments
  float l_reg[4], v_reg[4];
#pragma unroll
  for (int nf = 0; nf < 4; ++nf) {
    const int n = wave * 64 + nf * 16 + m16;
    l_reg[nf] = PRE ? l_ws[(size_t)b * NH + n] : l_sm[n];
    v_reg[nf] = V[n];
  }

  // ---- U B-fragments into registers, held for the whole kernel (R1-style) ----
  bf16x8 u_frag[4][8];
  if (PRE) {
    // linear per-wave reads: frag id = ((wave*4+nf)*8 + kk)*64 + lane
    const __bf16* uw = Uswz + ((size_t)(wave * 4 * 8 * 64) + lane) * 8;
#pragma unroll
    for (int nf = 0; nf < 4; ++nf)
#pragma unroll
      for (int kk = 0; kk < 8; ++kk)
        u_frag[nf][kk] = *(const bf16x8*)(uw + (size_t)((nf * 8 + kk) << 9));
  } else {
#pragma unroll
    for (int nf = 0; nf < 4; ++nf) {
      const int n = wave * 64 + nf * 16 + m16;
      const float* urow = U + (size_t)n * NH;
#pragma unroll
      for (int kk = 0; kk < 8; ++kk) {
        const float4 lo = *(const float4*)(urow + kk * 32 + quad * 8);
        const float4 hi = *(const float4*)(urow + kk * 32 + quad * 8 + 4);
        bf16x8 f;
        f[0] = (__bf16)lo.x; f[1] = (__bf16)lo.y;
        f[2] = (__bf16)lo.z; f[3] = (__bf16)lo.w;
        f[4] = (__bf16)hi.x; f[5] = (__bf16)hi.y;
        f[6] = (__bf16)hi.z; f[7] = (__bf16)hi.w;
        u_frag[nf][kk] = f;
      }
    }
  }

  float m_run  = -INFINITY;
  float Z      = 0.f;
  float pooled = 0.f;   // thread t owns h = t (unnormalized, relative to m_run)

  for (int tile = 0; tile < ntiles; ++tile) {
    const int s0   = s_begin + tile * TILE_S;
    const int rows = min(TILE_S, s_end - s0);

    // ---- stage fp32 -> bf16 LDS (regular cached loads: mem stays L3-warm across replays) ----
    const float4* src4 = (const float4*)(mem + ((size_t)b * NS + s0) * NH);
#pragma unroll
    for (int i = 0; i < 4; ++i) {
      const int f2  = i * 256 + t;
      const int row = f2 >> 5;
      const int c8  = (f2 & 31) * 8;
      bf16x8 pk;
      if (row < rows) {
        const float4 a = src4[f2 * 2];
        const float4 c = src4[f2 * 2 + 1];
        pk[0] = (__bf16)a.x; pk[1] = (__bf16)a.y;
        pk[2] = (__bf16)a.z; pk[3] = (__bf16)a.w;
        pk[4] = (__bf16)c.x; pk[5] = (__bf16)c.y;
        pk[6] = (__bf16)c.z; pk[7] = (__bf16)c.w;
      } else {
        pk = (bf16x8)(__bf16)0.f;
      }
      *(bf16x8*)&mem_sm[row][c8] = pk;
    }
    __syncthreads();

    // ---- MFMA: a[s,n] 32 rows x 64 cols per wave, operands all in regs/LDS ----
    f32x4 acc[2][4];
    const f32x4 fzero = {0.f, 0.f, 0.f, 0.f};
#pragma unroll
    for (int mt = 0; mt < 2; ++mt)
#pragma unroll
      for (int nf = 0; nf < 4; ++nf)
        acc[mt][nf] = fzero;

#pragma unroll
    for (int kk = 0; kk < 8; ++kk) {
      const int c = kk * 32 + quad * 8;
      bf16x8 a0 = *(const bf16x8*)&mem_sm[m16][c];
      bf16x8 a1 = *(const bf16x8*)&mem_sm[16 + m16][c];
#pragma unroll
      for (int nf = 0; nf < 4; ++nf) {
        acc[0][nf] = __builtin_amdgcn_mfma_f32_16x16x32_bf16(a0, u_frag[nf][kk], acc[0][nf], 0, 0, 0);
        acc[1][nf] = __builtin_amdgcn_mfma_f32_16x16x32_bf16(a1, u_frag[nf][kk], acc[1][nf], 0, 0, 0);
      }
    }

    // ---- p = sum_n tanh(a + l[n]) * V[n] over this wave's 64 n ----
    float p[2][4];
#pragma unroll
    for (int mt = 0; mt < 2; ++mt) {
#pragma unroll
      for (int reg = 0; reg < 4; ++reg) {
        float s = 0.f;
#pragma unroll
        for (int nf = 0; nf < 4; ++nf)
          s = fmaf(tanh_fast(acc[mt][nf][reg] + l_reg[nf]), v_reg[nf], s);
        p[mt][reg] = s;
      }
    }
#pragma unroll
    for (int off = 1; off < 16; off <<= 1) {
#pragma unroll
      for (int mt = 0; mt < 2; ++mt)
#pragma unroll
        for (int reg = 0; reg < 4; ++reg)
          p[mt][reg] += __shfl_xor(p[mt][reg], off);
    }
    if (m16 == 0) {
#pragma unroll
      for (int mt = 0; mt < 2; ++mt)
#pragma unroll
        for (int reg = 0; reg < 4; ++reg)
          swave_sm[wave][mt * 16 + quad * 4 + reg] = p[mt][reg];
    }
    __syncthreads();

    if (t < TILE_S)
      scores_sm[t] = swave_sm[0][t] + swave_sm[1][t] + swave_sm[2][t] + swave_sm[3][t];
    __syncthreads();

    // ---- online softmax + pooled update (all threads compute identical m/Z) ----
    float m_tile = -INFINITY;
    for (int r = 0; r < rows; ++r) m_tile = fmaxf(m_tile, scores_sm[r]);
    const float m_new = fmaxf(m_run, m_tile);
    const float fac   = __expf(m_run - m_new);
    float z_t = 0.f, pool_t = 0.f;
    for (int r = 0; r < rows; ++r) {
      const float e = __expf(scores_sm[r] - m_new);
      z_t += e;
      pool_t = fmaf(e, (float)mem_sm[r][t], pool_t);
    }
    Z      = Z * fac + z_t;
    pooled = pooled * fac + pool_t;
    m_run  = m_new;
    __syncthreads();
  }

  float* base = part + (size_t)blockIdx.x * WS_STRIDE;
  if (t == 0) { base[0] = m_run; base[1] = Z; }
  base[2 + t] = pooled;
}

// ---------------- Kernel 2: merge halves + MetaW projection ----------------
__global__ __launch_bounds__(256)
void merge_project(const float* __restrict__ part,
                   const float* __restrict__ MetaW,  // [4,H]
                   const float* __restrict__ Metab,  // [4]
                   float* __restrict__ out)          // [B,4]
{
  const int b    = blockIdx.x;
  const int t    = threadIdx.x;
  const int wave = t >> 6;
  const int lane = t & 63;

  __shared__ float pooled_sm[NH];

  const float* b0 = part + (size_t)(b * 2)     * WS_STRIDE;
  const float* b1 = part + (size_t)(b * 2 + 1) * WS_STRIDE;
  const float m0 = b0[0], Z0 = b0[1];
  const float m1 = b1[0], Z1 = b1[1];
  const float mm = fmaxf(m0, m1);
  const float w0 = __expf(m0 - mm);
  const float w1 = __expf(m1 - mm);
  const float Zi = 1.f / (Z0 * w0 + Z1 * w1);

  pooled_sm[t] = (b0[2 + t] * w0 + b1[2 + t] * w1) * Zi;
  __syncthreads();

  float s = 0.f;
#pragma unroll
  for (int i = 0; i < 4; ++i) {
    const int h = i * 64 + lane;
    s = fmaf(pooled_sm[h], MetaW[(size_t)wave * NH + h], s);
  }
#pragma unroll
  for (int off = 32; off > 0; off >>= 1)
    s += __shfl_down(s, off);
  if (lane == 0)
    out[b * 4 + wave] = s + Metab[wave];
}

extern "C" void kernel_launch(void* const* d_in, const int* in_sizes, int n_in,
                              void* d_out, int out_size, void* d_ws, size_t ws_size,
                              hipStream_t stream) {
  const float* mem   = (const float*)d_in[0];
  const float* lastm = (const float*)d_in[1];
  const float* U     = (const float*)d_in[2];
  const float* W     = (const float*)d_in[3];
  const float* V     = (const float*)d_in[4];
  const float* MetaW = (const float*)d_in[5];
  const float* Metab = (const float*)d_in[6];
  float* out = (float*)d_out;
  float* ws  = (float*)d_ws;

  float* part = ws + OFF_PART;

  if (ws_size >= (size_t)WS_FLOATS_PRE * sizeof(float)) {
    float*  l_ws = ws + OFF_L;
    __bf16* Uswz = (__bf16*)(ws + OFF_UB);
    hipLaunchKernelGGL(precompute, dim3(NB + 32), dim3(256), 0, stream,
                       lastm, W, U, l_ws, Uswz);
    hipLaunchKernelGGL(fused_meta_attn_part<true>, dim3(NPART), dim3(256), 0, stream,
                       mem, lastm, U, W, V, l_ws, Uswz, part);
  } else {
    hipLaunchKernelGGL(fused_meta_attn_part<false>, dim3(NPART), dim3(256), 0, stream,
                       mem, lastm, U, W, V, (const float*)nullptr, (const __bf16*)nullptr, part);
  }
  hipLaunchKernelGGL(merge_project, dim3(NB), dim3(256), 0, stream,
                     part, MetaW, Metab, out);
}